// Round 8
// baseline (337.219 us; speedup 1.0000x reference)
//
#include <hip/hip_runtime.h>
#include <hip/hip_bf16.h>

#define DEPTHL 2
#define DIMM   512
#define NHEADS 8
#define DHH    64
#define INNERD 512
#define MLPD   2048
#define BB     2
#define SEQL   2048
#define ROWS   (BB*SEQL)
#define MNEG   (-1.0e38f)
#define SCLQ   0.18033688f   /* 0.125 * log2(e), folded into Q */
#define NSPLIT 4
#define KPS    (SEQL / NSPLIT)
#define NCH    128           /* adain row-chunks */

typedef __attribute__((ext_vector_type(4))) float f32x4;
typedef __attribute__((ext_vector_type(8))) __bf16 bf16x8;

#define GLDS16(g, l) __builtin_amdgcn_global_load_lds((const __attribute__((address_space(1))) void*)(g), (__attribute__((address_space(3))) void*)(l), 16, 0, 0)

__device__ __forceinline__ unsigned short f2bf(float f) {
  union { float f; unsigned int u; } v; v.f = f;
  unsigned int r = v.u + 0x7fffu + ((v.u >> 16) & 1u);
  return (unsigned short)(r >> 16);
}
__device__ __forceinline__ float bf2f(unsigned short h) {
  union { unsigned int u; float f; } v; v.u = ((unsigned int)h) << 16; return v.f;
}
// packed RNE f32x2 -> bf16x2 (low = a, high = b)
__device__ __forceinline__ unsigned int cvtpk(float a, float b) {
  unsigned int r;
  asm("v_cvt_pk_bf16_f32 %0, %1, %2" : "=v"(r) : "v"(a), "v"(b));
  return r;
}

// ---------------- weight transpose fp32[K][N] -> bf16[N][K] ----------------
__global__ __launch_bounds__(256) void wtrans(const float* __restrict__ wsrc,
                                              unsigned short* __restrict__ wdst,
                                              int K, int N) {
  __shared__ float t[32][33];
  const float* src = wsrc + (size_t)blockIdx.z * K * N;
  unsigned short* dst = wdst + (size_t)blockIdx.z * K * N;
  int k0 = blockIdx.x * 32, n0 = blockIdx.y * 32;
  int tx = threadIdx.x & 31, ty = threadIdx.x >> 5;  // 32x8
#pragma unroll
  for (int j = 0; j < 32; j += 8)
    t[ty + j][tx] = src[(size_t)(k0 + ty + j) * N + n0 + tx];
  __syncthreads();
#pragma unroll
  for (int j = 0; j < 32; j += 8)
    dst[(size_t)(n0 + ty + j) * K + k0 + tx] = f2bf(t[tx][ty + j]);
}

// ---------------- adain ----------------
__global__ __launch_bounds__(512) void adain_p1(const float* __restrict__ x,
                                                float* __restrict__ p1, float* __restrict__ p2) {
  int d = threadIdx.x, c = blockIdx.x, b = blockIdx.y;  // c in [0,128), 16 rows each
  const float* xp = x + ((size_t)b * SEQL + c * 16) * DIMM + d;
  float s = 0.f, s2 = 0.f;
#pragma unroll
  for (int i = 0; i < 16; ++i) { float v = xp[(size_t)i * DIMM]; s += v; s2 += v * v; }
  p1[(b * NCH + c) * DIMM + d] = s;
  p2[(b * NCH + c) * DIMM + d] = s2;
}

__global__ __launch_bounds__(512) void adain_p2(const float* __restrict__ p1, const float* __restrict__ p2,
                                                const float* __restrict__ w, const float* __restrict__ bi,
                                                float* __restrict__ alpha, float* __restrict__ beta) {
  int d = threadIdx.x, b = blockIdx.x;
  float s = 0.f, s2 = 0.f;
  for (int c = 0; c < NCH; ++c) { s += p1[(b * NCH + c) * DIMM + d]; s2 += p2[(b * NCH + c) * DIMM + d]; }
  float mean = s * (1.0f / SEQL);
  float var = s2 * (1.0f / SEQL) - mean * mean;
  float a = w[b * DIMM + d] * rsqrtf(var + 1e-6f);
  alpha[b * DIMM + d] = a;
  beta[b * DIMM + d] = bi[b * DIMM + d] - mean * a;
}

__global__ __launch_bounds__(256) void adain_apply(const float* __restrict__ x,
                                                   const float* __restrict__ alpha, const float* __restrict__ beta,
                                                   unsigned short* __restrict__ hb) {
  int idx = blockIdx.x * 256 + threadIdx.x;  // over ROWS*DIMM = 2^21
  int d = idx & (DIMM - 1);
  int b = idx >> 20;  // SEQL*DIMM = 2^20
  hb[idx] = f2bf(x[idx] * alpha[b * DIMM + d] + beta[b * DIMM + d]);
}

// ---------------- mask -> additive float (0 or -1e38) ----------------
__global__ __launch_bounds__(256) void maskbuild(const int* __restrict__ mask, float* __restrict__ maskadd) {
  int i = blockIdx.x * 256 + threadIdx.x;  // B*N = 4096
  maskadd[i] = mask[i] ? 0.f : MNEG;
}

// ---------------- GEMM: out = A[M,Kt](bf16) @ Wt[N,Kt]^T(bf16) ----------------
// EPI: 0 = bf16 out, 1 = gelu->bf16 out, 2 = fp32 out + bias + resid, 3 = bf16 partial (split-K)
template <int EPI, int BN>
__global__ __launch_bounds__(256)
void gemm_k(const unsigned short* __restrict__ A,
            const unsigned short* __restrict__ Wt,
            const float* __restrict__ bias,
            const float* __restrict__ resid,
            float* __restrict__ outF,
            unsigned short* __restrict__ outB,
            unsigned short* __restrict__ part,
            int N, int Kt) {
  constexpr int NI = BN / 32;  // B frags / acc cols per wave
  __shared__ __align__(16) unsigned short As[2][128 * 32];
  __shared__ __align__(16) unsigned short Bs[2][BN * 32];
  const int tid = threadIdx.x;
  const int w = tid >> 6, lane = tid & 63;

  // XCD-aware remap within each z-slice
  unsigned int f = blockIdx.y * gridDim.x + blockIdx.x;
  unsigned int grp = f & 7u, idx = f >> 3;
  unsigned int rpx = gridDim.y >> 3;
  unsigned int by = grp * rpx + idx / gridDim.x;
  unsigned int bx = idx % gridDim.x;

  const int bm = by * 128, bn = bx * BN;
  const int wm = (w >> 1) * 64, wn = (w & 1) * (BN / 2);

  // split-K range
  const int nsplit = gridDim.z, sp = blockIdx.z;
  const int Kc = Kt / nsplit;
  const int kbeg = sp * Kc, kend = kbeg + Kc;

  f32x4 acc[4][NI] = {};

  auto stage = [&](int buf, int k0) {
#pragma unroll
    for (int j = 0; j < 2; ++j) {
      int r = w * 32 + (lane >> 2) + j * 16;
      int cl = (lane & 3) ^ ((r >> 1) & 3);
      GLDS16(A + (size_t)(bm + r) * Kt + k0 + cl * 8, &As[buf][(w * 32 + j * 16) * 32]);
    }
    if (BN == 128) {
#pragma unroll
      for (int j = 0; j < 2; ++j) {
        int r = w * 32 + (lane >> 2) + j * 16;
        int cl = (lane & 3) ^ ((r >> 1) & 3);
        GLDS16(Wt + (size_t)(bn + r) * Kt + k0 + cl * 8, &Bs[buf][(w * 32 + j * 16) * 32]);
      }
    } else {
      int r = w * 16 + (lane >> 2);
      int cl = (lane & 3) ^ ((r >> 1) & 3);
      GLDS16(Wt + (size_t)(bn + r) * Kt + k0 + cl * 8, &Bs[buf][(w * 16) * 32]);
    }
  };

  stage(0, kbeg);
  __syncthreads();
  int cur = 0;

  for (int k0 = kbeg; k0 < kend; k0 += 32) {
    if (k0 + 32 < kend) stage(cur ^ 1, k0 + 32);
    bf16x8 af[4], bfr[NI];
#pragma unroll
    for (int i = 0; i < 4; ++i) {
      int ar = wm + i * 16 + (lane & 15);
      int ac = (lane >> 4) ^ ((ar >> 1) & 3);
      af[i] = *(const bf16x8*)&As[cur][ar * 32 + ac * 8];
    }
#pragma unroll
    for (int i = 0; i < NI; ++i) {
      int br = wn + i * 16 + (lane & 15);
      int bc = (lane >> 4) ^ ((br >> 1) & 3);
      bfr[i] = *(const bf16x8*)&Bs[cur][br * 32 + bc * 8];
    }
#pragma unroll
    for (int mi = 0; mi < 4; ++mi)
#pragma unroll
      for (int ni = 0; ni < NI; ++ni)
        acc[mi][ni] = __builtin_amdgcn_mfma_f32_16x16x32_bf16(af[mi], bfr[ni], acc[mi][ni], 0, 0, 0);
    __syncthreads();
    cur ^= 1;
  }

  const size_t MN = (size_t)gridDim.y * 128 * N;
#pragma unroll
  for (int mi = 0; mi < 4; ++mi) {
#pragma unroll
    for (int ni = 0; ni < NI; ++ni) {
#pragma unroll
      for (int r = 0; r < 4; ++r) {
        int row = bm + wm + mi * 16 + (lane >> 4) * 4 + r;
        int col = bn + wn + ni * 16 + (lane & 15);
        float v = acc[mi][ni][r];
        size_t o = (size_t)row * N + col;
        if (EPI == 3) {
          part[(size_t)sp * MN + o] = f2bf(v);
        } else {
          if (bias) v += bias[col];
          if (EPI == 1) v = 0.5f * v * (1.0f + erff(v * 0.70710678118f));
          if (EPI == 2) outF[o] = v + resid[o];
          else if (EPI != 2) outB[o] = f2bf(v);
        }
      }
    }
  }
}

// ---------------- split-K combine (bf16 partials): out = sum(part) + bias + resid ----------------
template <int NS>
__global__ __launch_bounds__(256) void comb_k(const unsigned short* __restrict__ part,
                                              const float* __restrict__ bias,
                                              const float* __restrict__ resid,
                                              float* __restrict__ outF) {
  size_t idx = ((size_t)blockIdx.x * 256 + threadIdx.x) * 4;  // over ROWS*512
  int col = (int)(idx & 511);
  float a0 = 0.f, a1 = 0.f, a2 = 0.f, a3 = 0.f;
#pragma unroll
  for (int s = 0; s < NS; ++s) {
    uint2 v = *(const uint2*)&part[(size_t)s * ROWS * 512 + idx];
    a0 += bf2f(v.x & 0xffff); a1 += bf2f(v.x >> 16);
    a2 += bf2f(v.y & 0xffff); a3 += bf2f(v.y >> 16);
  }
  f32x4 b = *(const f32x4*)&bias[col];
  f32x4 rs = *(const f32x4*)&resid[idx];
  f32x4 o;
  o[0] = a0 + b[0] + rs[0]; o[1] = a1 + b[1] + rs[1];
  o[2] = a2 + b[2] + rs[2]; o[3] = a3 + b[3] + rs[3];
  *(f32x4*)&outF[idx] = o;
}

// ---------------- fused qkv prep: q(scaled)/k copy, v transpose, v column-sum atomics ----------------
__global__ __launch_bounds__(256) void qkv_prep(const unsigned short* __restrict__ qkv,
                                                unsigned short* __restrict__ q,
                                                unsigned short* __restrict__ k,
                                                unsigned short* __restrict__ vt,
                                                float* __restrict__ vsum) {
  __shared__ unsigned short t[64][65];
  const int bh = blockIdx.x, nt = blockIdx.y;
  const int b = bh >> 3, h = bh & 7;
  const int n0 = nt * 64;
  const int tid = threadIdx.x;
  const int nloc = tid >> 3, dh0 = (tid & 7) * 8;
#pragma unroll
  for (int j = 0; j < 2; ++j) {
    int n = nloc + j * 32;
    size_t src = (size_t)(b * SEQL + n0 + n) * 1536 + h * 64 + dh0;
    size_t dst = ((size_t)bh * SEQL + n0 + n) * 64 + dh0;
    uint4 qv = *(const uint4*)&qkv[src];
    uint4 qs;
    qs.x = cvtpk(bf2f(qv.x & 0xffff) * SCLQ, bf2f(qv.x >> 16) * SCLQ);
    qs.y = cvtpk(bf2f(qv.y & 0xffff) * SCLQ, bf2f(qv.y >> 16) * SCLQ);
    qs.z = cvtpk(bf2f(qv.z & 0xffff) * SCLQ, bf2f(qv.z >> 16) * SCLQ);
    qs.w = cvtpk(bf2f(qv.w & 0xffff) * SCLQ, bf2f(qv.w >> 16) * SCLQ);
    *(uint4*)&q[dst] = qs;
    *(uint4*)&k[dst] = *(const uint4*)&qkv[src + INNERD];
    uint4 vv = *(const uint4*)&qkv[src + 2 * INNERD];
    unsigned short* tr = &t[n][dh0];
    tr[0] = (unsigned short)(vv.x & 0xffff); tr[1] = (unsigned short)(vv.x >> 16);
    tr[2] = (unsigned short)(vv.y & 0xffff); tr[3] = (unsigned short)(vv.y >> 16);
    tr[4] = (unsigned short)(vv.z & 0xffff); tr[5] = (unsigned short)(vv.z >> 16);
    tr[6] = (unsigned short)(vv.w & 0xffff); tr[7] = (unsigned short)(vv.w >> 16);
  }
  __syncthreads();
#pragma unroll
  for (int j = 0; j < 16; ++j) {
    int i = tid + j * 256;
    int dh = i >> 6, n = i & 63;
    vt[((size_t)bh * DHH + dh) * SEQL + n0 + n] = t[n][dh];
  }
  // per-block V column sums -> atomics (divided by SEQL in attn_combine)
  int dh = tid >> 2, seg = tid & 3;
  float s = 0.f;
#pragma unroll
  for (int i = 0; i < 16; ++i) s += bf2f(t[seg * 16 + i][dh]);
  s += __shfl_xor(s, 1);
  s += __shfl_xor(s, 2);
  if (seg == 0) atomicAdd(&vsum[bh * 64 + dh], s);
}

// ---------------- flash attention: dbuf K/V, mask via MFMA C-init, l via ones-MFMA ----------------
__global__ __launch_bounds__(256, 4)
void attn_split(const unsigned short* __restrict__ qg,
                const unsigned short* __restrict__ kg,
                const unsigned short* __restrict__ vtg,
                const float* __restrict__ maskadd,
                unsigned short* __restrict__ opart,  // [NSPLIT][16][SEQL][DHH] bf16 (unnormalized)
                float* __restrict__ lpart) {        // [NSPLIT][16][SEQL]
  __shared__ __align__(16) unsigned short Ks[2][64 * 64];
  __shared__ __align__(16) unsigned short Vts[2][64 * 64];
  __shared__ __align__(16) unsigned short Ps[4 * 16 * 64];
  const int tid = threadIdx.x, w = tid >> 6, lane = tid & 63;
  const int g = lane >> 4, c = lane & 15;
  const int bh = blockIdx.y, b = bh >> 3;
  const int qt = blockIdx.x;
  const int split = blockIdx.z;
  const int kv0 = split * KPS;
  const int q0 = qt * 64 + w * 16;
  const float* maskb = maskadd + b * SEQL;

  bf16x8 qf[2];
#pragma unroll
  for (int kb = 0; kb < 2; ++kb)
    qf[kb] = *(const bf16x8*)&qg[((size_t)bh * SEQL + q0 + c) * DHH + kb * 32 + g * 8];

  const __bf16 one1 = (__bf16)1.0f;
  const bf16x8 ones = {one1, one1, one1, one1, one1, one1, one1, one1};

  f32x4 o[4] = {};
  f32x4 lones = {};  // row-sums of P via ones-MFMA
  unsigned short* myP = &Ps[w * 1024];

  auto stageA = [&](int buf, int kt) {
#pragma unroll
    for (int j = 0; j < 2; ++j) {
      int r = w * 16 + j * 8 + (lane >> 3);
      int cl = (lane & 7) ^ (r & 7);
      GLDS16(kg + ((size_t)bh * SEQL + kv0 + kt * 64 + r) * DHH + cl * 8, &Ks[buf][(w * 16 + j * 8) * 64]);
      GLDS16(vtg + ((size_t)bh * DHH + r) * SEQL + kv0 + kt * 64 + cl * 8, &Vts[buf][(w * 16 + j * 8) * 64]);
    }
  };

  stageA(0, 0);
  __syncthreads();
  int cur = 0;

  for (int kt = 0; kt < KPS / 64; ++kt) {
    if (kt + 1 < KPS / 64) stageA(cur ^ 1, kt + 1);  // prefetch next K/V tile

    // S^T = K @ Q^T + mask (C-init): lane holds S[k = nt*16+g*4+r][q = c], log2 domain
    f32x4 sT[4];
#pragma unroll
    for (int nt = 0; nt < 4; ++nt)
      sT[nt] = *(const f32x4*)&maskb[kv0 + kt * 64 + nt * 16 + g * 4];
#pragma unroll
    for (int nt = 0; nt < 4; ++nt) {
#pragma unroll
      for (int kb = 0; kb < 2; ++kb) {
        int kr = nt * 16 + c;
        int cs = (kb * 4 + g) ^ (kr & 7);
        bf16x8 kf = *(const bf16x8*)&Ks[cur][kr * 64 + cs * 8];
        sT[nt] = __builtin_amdgcn_mfma_f32_16x16x32_bf16(kf, qf[kb], sT[nt], 0, 0, 0);
      }
    }

    // p = exp2(S) (fixed m = 0; masked entries -> 0), pack, write to wave-private LDS
#pragma unroll
    for (int nt = 0; nt < 4; ++nt) {
      float pv0 = exp2f(sT[nt][0]), pv1 = exp2f(sT[nt][1]);
      float pv2 = exp2f(sT[nt][2]), pv3 = exp2f(sT[nt][3]);
      unsigned int lo = cvtpk(pv0, pv1), hi = cvtpk(pv2, pv3);
      int off = c * 64 + (((nt * 2 + (g >> 1)) ^ (c & 7)) << 3) + ((g & 1) << 2);
      *(uint2*)(myP + off) = make_uint2(lo, hi);
    }

    // PV + l: A = P, B = Vt (and ones for the row-sum)
#pragma unroll
    for (int kb = 0; kb < 2; ++kb) {
      bf16x8 pf = *(const bf16x8*)&myP[c * 64 + (((kb * 4 + g) ^ (c & 7)) << 3)];
      lones = __builtin_amdgcn_mfma_f32_16x16x32_bf16(pf, ones, lones, 0, 0, 0);
#pragma unroll
      for (int ni = 0; ni < 4; ++ni) {
        int vr = ni * 16 + c;
        int vc = (kb * 4 + g) ^ (vr & 7);
        bf16x8 vf = *(const bf16x8*)&Vts[cur][vr * 64 + vc * 8];
        o[ni] = __builtin_amdgcn_mfma_f32_16x16x32_bf16(pf, vf, o[ni], 0, 0, 0);
      }
    }
    __syncthreads();  // next tile's loads drained; everyone done with buf[cur]
    cur ^= 1;
  }

  const size_t pb = ((size_t)split * 16 + bh) * SEQL;
#pragma unroll
  for (int ni = 0; ni < 4; ++ni)
#pragma unroll
    for (int r = 0; r < 4; ++r)
      opart[(pb + q0 + g * 4 + r) * DHH + ni * 16 + c] = f2bf(o[ni][r]);
  if (c == 0) {
#pragma unroll
    for (int r = 0; r < 4; ++r) lpart[pb + q0 + g * 4 + r] = lones[r];
  }
}

__global__ __launch_bounds__(256) void attn_combine(const unsigned short* __restrict__ opart,
                                                    const float* __restrict__ lpart,
                                                    const float* __restrict__ maskadd,
                                                    const float* __restrict__ vsum,
                                                    unsigned short* __restrict__ ctx) {
  int idx = blockIdx.x * 256 + threadIdx.x;  // 16*SEQL*16 threads, 4 d each
  int dq = idx & 15;
  int q = (idx >> 4) & (SEQL - 1);
  int bh = idx >> 15;
  int d0 = dq * 4;
  int b = bh >> 3, h = bh & 7;
  float o0 = 0.f, o1 = 0.f, o2 = 0.f, o3 = 0.f, L = 0.f;
#pragma unroll
  for (int s = 0; s < NSPLIT; ++s) {
    size_t base = ((size_t)s * 16 + bh) * SEQL + q;
    L += lpart[base];
    uint2 v = *(const uint2*)&opart[base * DHH + d0];
    o0 += bf2f(v.x & 0xffff); o1 += bf2f(v.x >> 16);
    o2 += bf2f(v.y & 0xffff); o3 += bf2f(v.y >> 16);
  }
  float r = 1.0f / L;
  o0 *= r; o1 *= r; o2 *= r; o3 *= r;
  if (maskadd[b * SEQL + q] != 0.f) {  // masked q: reference gives uniform attention = mean(V)
    f32x4 vm = *(const f32x4*)&vsum[bh * 64 + d0];
    o0 = vm[0] * (1.0f / SEQL); o1 = vm[1] * (1.0f / SEQL);
    o2 = vm[2] * (1.0f / SEQL); o3 = vm[3] * (1.0f / SEQL);
  }
  *(uint2*)&ctx[((size_t)(b * SEQL + q)) * INNERD + h * 64 + d0] =
      make_uint2(cvtpk(o0, o1), cvtpk(o2, o3));
}

// ---------------- host ----------------
extern "C" void kernel_launch(void* const* d_in, const int* in_sizes, int n_in,
                              void* d_out, int out_size, void* d_ws, size_t ws_size,
                              hipStream_t stream) {
  (void)in_sizes; (void)n_in; (void)out_size;
  const float* x_in = (const float*)d_in[0];
  const int* mask = (const int*)d_in[1];
  const float* qkv_w = (const float*)d_in[2];
  const float* out_w = (const float*)d_in[3];
  const float* out_b = (const float*)d_in[4];
  const float* ff_w1 = (const float*)d_in[5];
  const float* ff_b1 = (const float*)d_in[6];
  const float* ff_w2 = (const float*)d_in[7];
  const float* ff_b2 = (const float*)d_in[8];
  const float* ad1w = (const float*)d_in[9];
  const float* ad1b = (const float*)d_in[10];
  const float* ad2w = (const float*)d_in[11];
  const float* ad2b = (const float*)d_in[12];

  char* ws = (char*)d_ws;
  size_t off = 0;
  auto alloc = [&](size_t bytes) {
    char* p = ws + off;
    off = (off + bytes + 255) & ~(size_t)255;
    return p;
  };
  unsigned short* wtQ = (unsigned short*)alloc((size_t)DEPTHL * 1536 * 512 * 2);
  unsigned short* wtO = (unsigned short*)alloc((size_t)DEPTHL * 512 * 512 * 2);
  unsigned short* wtF1 = (unsigned short*)alloc((size_t)DEPTHL * 2048 * 512 * 2);
  unsigned short* wtF2 = (unsigned short*)alloc((size_t)DEPTHL * 512 * 2048 * 2);
  float* xc = (float*)alloc((size_t)ROWS * DIMM * 4);
  unsigned short* hbf = (unsigned short*)alloc((size_t)ROWS * DIMM * 2);
  unsigned short* qkvbf = (unsigned short*)alloc((size_t)ROWS * 1536 * 2);
  char* region2 = alloc((size_t)4 * 16 * SEQL * DHH * 2);  // q,k,vt,ctx OR h1
  unsigned short* qb = (unsigned short*)region2;
  unsigned short* kb = qb + (size_t)16 * SEQL * DHH;
  unsigned short* vtb = kb + (size_t)16 * SEQL * DHH;
  unsigned short* ctxb = vtb + (size_t)16 * SEQL * DHH;
  unsigned short* h1bf = (unsigned short*)region2;  // aliases q/k/vt/ctx (disjoint lifetime)
  float* p1 = (float*)alloc((size_t)BB * NCH * DIMM * 4);
  float* p2 = (float*)alloc((size_t)BB * NCH * DIMM * 4);
  float* alpha = (float*)alloc((size_t)BB * DIMM * 4);
  float* beta = (float*)alloc((size_t)BB * DIMM * 4);
  float* maskadd = (float*)alloc((size_t)BB * SEQL * 4);
  unsigned short* opart = (unsigned short*)alloc((size_t)NSPLIT * 16 * SEQL * DHH * 2);
  float* lpart = (float*)alloc((size_t)NSPLIT * 16 * SEQL * 4);
  float* vsum = (float*)alloc((size_t)16 * 64 * 4);
  unsigned short* part = (unsigned short*)alloc((size_t)4 * ROWS * 512 * 2);  // 16MB bf16 split-K partials
  const bool fits = off <= ws_size;  // graceful fallback if workspace too small

  // x working copy
  hipMemcpyAsync(xc, x_in, (size_t)ROWS * DIMM * 4, hipMemcpyDeviceToDevice, stream);

  // weights -> bf16 transposed [N][K]
  wtrans<<<dim3(512 / 32, 1536 / 32, DEPTHL), 256, 0, stream>>>(qkv_w, wtQ, 512, 1536);
  wtrans<<<dim3(512 / 32, 512 / 32, DEPTHL), 256, 0, stream>>>(out_w, wtO, 512, 512);
  wtrans<<<dim3(512 / 32, 2048 / 32, DEPTHL), 256, 0, stream>>>(ff_w1, wtF1, 512, 2048);
  wtrans<<<dim3(2048 / 32, 512 / 32, DEPTHL), 256, 0, stream>>>(ff_w2, wtF2, 2048, 512);
  maskbuild<<<BB * SEQL / 256, 256, 0, stream>>>(mask, maskadd);

  for (int l = 0; l < DEPTHL; ++l) {
    // adain 1
    adain_p1<<<dim3(NCH, BB), 512, 0, stream>>>(xc, p1, p2);
    adain_p2<<<BB, 512, 0, stream>>>(p1, p2, ad1w + l * BB * DIMM, ad1b + l * BB * DIMM, alpha, beta);
    adain_apply<<<8192, 256, 0, stream>>>(xc, alpha, beta, hbf);
    // qkv: [4096,512] x [512,1536] -> bf16
    gemm_k<0, 64><<<dim3(1536 / 64, ROWS / 128), 256, 0, stream>>>(
        hbf, wtQ + (size_t)l * 1536 * 512, nullptr, nullptr, nullptr, qkvbf, nullptr, 1536, 512);
    hipMemsetAsync(vsum, 0, 16 * 64 * 4, stream);
    qkv_prep<<<dim3(16, 32), 256, 0, stream>>>(qkvbf, qb, kb, vtb, vsum);
    attn_split<<<dim3(SEQL / 64, 16, NSPLIT), 256, 0, stream>>>(qb, kb, vtb, maskadd, opart, lpart);
    attn_combine<<<16 * SEQL * 16 / 256, 256, 0, stream>>>(opart, lpart, maskadd, vsum, ctxb);
    // out proj + residual (in place on xc)
    if (fits) {
      gemm_k<3, 64><<<dim3(512 / 64, ROWS / 128, 2), 256, 0, stream>>>(
          ctxb, wtO + (size_t)l * 512 * 512, nullptr, nullptr, nullptr, nullptr, part, 512, 512);
      comb_k<2><<<ROWS * 512 / 1024, 256, 0, stream>>>(part, out_b + l * DIMM, xc, xc);
    } else {
      gemm_k<2, 64><<<dim3(512 / 64, ROWS / 128), 256, 0, stream>>>(
          ctxb, wtO + (size_t)l * 512 * 512, out_b + l * DIMM, xc, xc, nullptr, nullptr, 512, 512);
    }
    // adain 2
    adain_p1<<<dim3(NCH, BB), 512, 0, stream>>>(xc, p1, p2);
    adain_p2<<<BB, 512, 0, stream>>>(p1, p2, ad2w + l * BB * DIMM, ad2b + l * BB * DIMM, alpha, beta);
    adain_apply<<<8192, 256, 0, stream>>>(xc, alpha, beta, hbf);
    // ff1 (gelu) -> h1
    gemm_k<1, 64><<<dim3(2048 / 64, ROWS / 128), 256, 0, stream>>>(
        hbf, wtF1 + (size_t)l * 2048 * 512, ff_b1 + l * MLPD, nullptr, nullptr, h1bf, nullptr, 2048, 512);
    // ff2 + residual
    float* xout = (l == DEPTHL - 1) ? (float*)d_out : xc;
    if (fits) {
      gemm_k<3, 64><<<dim3(512 / 64, ROWS / 128, 4), 256, 0, stream>>>(
          h1bf, wtF2 + (size_t)l * 512 * 2048, nullptr, nullptr, nullptr, nullptr, part, 512, 2048);
      comb_k<4><<<ROWS * 512 / 1024, 256, 0, stream>>>(part, ff_b2 + l * DIMM, xc, xout);
    } else {
      gemm_k<2, 64><<<dim3(512 / 64, ROWS / 128), 256, 0, stream>>>(
          h1bf, wtF2 + (size_t)l * 512 * 2048, ff_b2 + l * DIMM, xc, xout, nullptr, nullptr, 512, 2048);
    }
  }
}

// Round 9
// 312.568 us; speedup vs baseline: 1.0789x; 1.0789x over previous
//
#include <hip/hip_runtime.h>
#include <hip/hip_bf16.h>

#define DEPTHL 2
#define DIMM   512
#define NHEADS 8
#define DHH    64
#define INNERD 512
#define MLPD   2048
#define BB     2
#define SEQL   2048
#define ROWS   (BB*SEQL)
#define MNEG   (-1.0e38f)
#define SCLQ   0.18033688f   /* 0.125 * log2(e), folded into Q */
#define NSPLIT 4
#define KPS    (SEQL / NSPLIT)

typedef __attribute__((ext_vector_type(4))) float f32x4;
typedef __attribute__((ext_vector_type(8))) __bf16 bf16x8;

#define GLDS16(g, l) __builtin_amdgcn_global_load_lds((const __attribute__((address_space(1))) void*)(g), (__attribute__((address_space(3))) void*)(l), 16, 0, 0)

__device__ __forceinline__ unsigned short f2bf(float f) {
  union { float f; unsigned int u; } v; v.f = f;
  unsigned int r = v.u + 0x7fffu + ((v.u >> 16) & 1u);
  return (unsigned short)(r >> 16);
}
__device__ __forceinline__ float bf2f(unsigned short h) {
  union { unsigned int u; float f; } v; v.u = ((unsigned int)h) << 16; return v.f;
}
// packed RNE f32x2 -> bf16x2 (low = a, high = b)
__device__ __forceinline__ unsigned int cvtpk(float a, float b) {
  unsigned int r;
  asm("v_cvt_pk_bf16_f32 %0, %1, %2" : "=v"(r) : "v"(a), "v"(b));
  return r;
}

// ---------------- weight transpose fp32[K][N] -> bf16[N][K] ----------------
__global__ __launch_bounds__(256) void wtrans(const float* __restrict__ wsrc,
                                              unsigned short* __restrict__ wdst,
                                              int K, int N) {
  __shared__ float t[32][33];
  const float* src = wsrc + (size_t)blockIdx.z * K * N;
  unsigned short* dst = wdst + (size_t)blockIdx.z * K * N;
  int k0 = blockIdx.x * 32, n0 = blockIdx.y * 32;
  int tx = threadIdx.x & 31, ty = threadIdx.x >> 5;  // 32x8
#pragma unroll
  for (int j = 0; j < 32; j += 8)
    t[ty + j][tx] = src[(size_t)(k0 + ty + j) * N + n0 + tx];
  __syncthreads();
#pragma unroll
  for (int j = 0; j < 32; j += 8)
    dst[(size_t)(n0 + ty + j) * K + k0 + tx] = f2bf(t[tx][ty + j]);
}

// ---------------- adain (32 chunks of 64 rows — proven scheme) ----------------
__global__ __launch_bounds__(512) void adain_p1(const float* __restrict__ x,
                                                float* __restrict__ p1, float* __restrict__ p2) {
  int d = threadIdx.x, c = blockIdx.x, b = blockIdx.y;
  const float* xp = x + ((size_t)b * SEQL + c * 64) * DIMM + d;
  float s = 0.f, s2 = 0.f;
  for (int i = 0; i < 64; ++i) { float v = xp[(size_t)i * DIMM]; s += v; s2 += v * v; }
  p1[(b * 32 + c) * DIMM + d] = s;
  p2[(b * 32 + c) * DIMM + d] = s2;
}

__global__ __launch_bounds__(512) void adain_p2(const float* __restrict__ p1, const float* __restrict__ p2,
                                                const float* __restrict__ w, const float* __restrict__ bi,
                                                float* __restrict__ alpha, float* __restrict__ beta) {
  int d = threadIdx.x, b = blockIdx.x;
  float s = 0.f, s2 = 0.f;
  for (int c = 0; c < 32; ++c) { s += p1[(b * 32 + c) * DIMM + d]; s2 += p2[(b * 32 + c) * DIMM + d]; }
  float mean = s * (1.0f / SEQL);
  float var = s2 * (1.0f / SEQL) - mean * mean;
  float a = w[b * DIMM + d] * rsqrtf(var + 1e-6f);
  alpha[b * DIMM + d] = a;
  beta[b * DIMM + d] = bi[b * DIMM + d] - mean * a;
}

__global__ __launch_bounds__(256) void adain_apply(const float* __restrict__ x,
                                                   const float* __restrict__ alpha, const float* __restrict__ beta,
                                                   unsigned short* __restrict__ hb) {
  int idx = blockIdx.x * 256 + threadIdx.x;  // over ROWS*DIMM = 2^21
  int d = idx & (DIMM - 1);
  int b = idx >> 20;  // SEQL*DIMM = 2^20
  hb[idx] = f2bf(x[idx] * alpha[b * DIMM + d] + beta[b * DIMM + d]);
}

// ---------------- mask -> additive float (0 or -1e38) ----------------
__global__ __launch_bounds__(256) void maskbuild(const int* __restrict__ mask, float* __restrict__ maskadd) {
  int i = blockIdx.x * 256 + threadIdx.x;  // B*N = 4096
  maskadd[i] = mask[i] ? 0.f : MNEG;
}

// ---------------- GEMM: out = A[M,Kt](bf16) @ Wt[N,Kt]^T(bf16) ----------------
// EPI: 0 = bf16 out, 1 = gelu->bf16 out, 2 = fp32 out + bias + resid, 3 = bf16 partial (split-K)
template <int EPI, int BN>
__global__ __launch_bounds__(256)
void gemm_k(const unsigned short* __restrict__ A,
            const unsigned short* __restrict__ Wt,
            const float* __restrict__ bias,
            const float* __restrict__ resid,
            float* __restrict__ outF,
            unsigned short* __restrict__ outB,
            unsigned short* __restrict__ part,
            int N, int Kt) {
  constexpr int NI = BN / 32;  // B frags / acc cols per wave
  __shared__ __align__(16) unsigned short As[2][128 * 32];
  __shared__ __align__(16) unsigned short Bs[2][BN * 32];
  const int tid = threadIdx.x;
  const int w = tid >> 6, lane = tid & 63;

  // XCD-aware remap within each z-slice
  unsigned int f = blockIdx.y * gridDim.x + blockIdx.x;
  unsigned int grp = f & 7u, idx = f >> 3;
  unsigned int rpx = gridDim.y >> 3;
  unsigned int by = grp * rpx + idx / gridDim.x;
  unsigned int bx = idx % gridDim.x;

  const int bm = by * 128, bn = bx * BN;
  const int wm = (w >> 1) * 64, wn = (w & 1) * (BN / 2);

  // split-K range
  const int nsplit = gridDim.z, sp = blockIdx.z;
  const int Kc = Kt / nsplit;
  const int kbeg = sp * Kc, kend = kbeg + Kc;

  f32x4 acc[4][NI] = {};

  auto stage = [&](int buf, int k0) {
#pragma unroll
    for (int j = 0; j < 2; ++j) {
      int r = w * 32 + (lane >> 2) + j * 16;
      int cl = (lane & 3) ^ ((r >> 1) & 3);
      GLDS16(A + (size_t)(bm + r) * Kt + k0 + cl * 8, &As[buf][(w * 32 + j * 16) * 32]);
    }
    if (BN == 128) {
#pragma unroll
      for (int j = 0; j < 2; ++j) {
        int r = w * 32 + (lane >> 2) + j * 16;
        int cl = (lane & 3) ^ ((r >> 1) & 3);
        GLDS16(Wt + (size_t)(bn + r) * Kt + k0 + cl * 8, &Bs[buf][(w * 32 + j * 16) * 32]);
      }
    } else {
      int r = w * 16 + (lane >> 2);
      int cl = (lane & 3) ^ ((r >> 1) & 3);
      GLDS16(Wt + (size_t)(bn + r) * Kt + k0 + cl * 8, &Bs[buf][(w * 16) * 32]);
    }
  };

  stage(0, kbeg);
  __syncthreads();
  int cur = 0;

  for (int k0 = kbeg; k0 < kend; k0 += 32) {
    if (k0 + 32 < kend) stage(cur ^ 1, k0 + 32);
    bf16x8 af[4], bfr[NI];
#pragma unroll
    for (int i = 0; i < 4; ++i) {
      int ar = wm + i * 16 + (lane & 15);
      int ac = (lane >> 4) ^ ((ar >> 1) & 3);
      af[i] = *(const bf16x8*)&As[cur][ar * 32 + ac * 8];
    }
#pragma unroll
    for (int i = 0; i < NI; ++i) {
      int br = wn + i * 16 + (lane & 15);
      int bc = (lane >> 4) ^ ((br >> 1) & 3);
      bfr[i] = *(const bf16x8*)&Bs[cur][br * 32 + bc * 8];
    }
#pragma unroll
    for (int mi = 0; mi < 4; ++mi)
#pragma unroll
      for (int ni = 0; ni < NI; ++ni)
        acc[mi][ni] = __builtin_amdgcn_mfma_f32_16x16x32_bf16(af[mi], bfr[ni], acc[mi][ni], 0, 0, 0);
    __syncthreads();
    cur ^= 1;
  }

  const size_t MN = (size_t)gridDim.y * 128 * N;
#pragma unroll
  for (int mi = 0; mi < 4; ++mi) {
#pragma unroll
    for (int ni = 0; ni < NI; ++ni) {
#pragma unroll
      for (int r = 0; r < 4; ++r) {
        int row = bm + wm + mi * 16 + (lane >> 4) * 4 + r;
        int col = bn + wn + ni * 16 + (lane & 15);
        float v = acc[mi][ni][r];
        size_t o = (size_t)row * N + col;
        if (EPI == 3) {
          part[(size_t)sp * MN + o] = f2bf(v);
        } else {
          if (bias) v += bias[col];
          if (EPI == 1) v = 0.5f * v * (1.0f + erff(v * 0.70710678118f));
          if (EPI == 2) outF[o] = v + resid[o];
          else if (EPI != 2) outB[o] = f2bf(v);
        }
      }
    }
  }
}

// ---------------- split-K combine (bf16 partials): out = sum(part) + bias + resid ----------------
template <int NS>
__global__ __launch_bounds__(256) void comb_k(const unsigned short* __restrict__ part,
                                              const float* __restrict__ bias,
                                              const float* __restrict__ resid,
                                              float* __restrict__ outF) {
  size_t idx = ((size_t)blockIdx.x * 256 + threadIdx.x) * 4;  // over ROWS*512
  int col = (int)(idx & 511);
  float a0 = 0.f, a1 = 0.f, a2 = 0.f, a3 = 0.f;
#pragma unroll
  for (int s = 0; s < NS; ++s) {
    uint2 v = *(const uint2*)&part[(size_t)s * ROWS * 512 + idx];
    a0 += bf2f(v.x & 0xffff); a1 += bf2f(v.x >> 16);
    a2 += bf2f(v.y & 0xffff); a3 += bf2f(v.y >> 16);
  }
  f32x4 b = *(const f32x4*)&bias[col];
  f32x4 rs = *(const f32x4*)&resid[idx];
  f32x4 o;
  o[0] = a0 + b[0] + rs[0]; o[1] = a1 + b[1] + rs[1];
  o[2] = a2 + b[2] + rs[2]; o[3] = a3 + b[3] + rs[3];
  *(f32x4*)&outF[idx] = o;
}

// ---------------- fused qkv prep: q(scaled)/k copy, v transpose, v column-sum atomics ----------------
__global__ __launch_bounds__(256) void qkv_prep(const unsigned short* __restrict__ qkv,
                                                unsigned short* __restrict__ q,
                                                unsigned short* __restrict__ k,
                                                unsigned short* __restrict__ vt,
                                                float* __restrict__ vsum) {
  __shared__ unsigned short t[64][65];
  const int bh = blockIdx.x, nt = blockIdx.y;
  const int b = bh >> 3, h = bh & 7;
  const int n0 = nt * 64;
  const int tid = threadIdx.x;
  const int nloc = tid >> 3, dh0 = (tid & 7) * 8;
#pragma unroll
  for (int j = 0; j < 2; ++j) {
    int n = nloc + j * 32;
    size_t src = (size_t)(b * SEQL + n0 + n) * 1536 + h * 64 + dh0;
    size_t dst = ((size_t)bh * SEQL + n0 + n) * 64 + dh0;
    uint4 qv = *(const uint4*)&qkv[src];
    uint4 qs;
    qs.x = cvtpk(bf2f(qv.x & 0xffff) * SCLQ, bf2f(qv.x >> 16) * SCLQ);
    qs.y = cvtpk(bf2f(qv.y & 0xffff) * SCLQ, bf2f(qv.y >> 16) * SCLQ);
    qs.z = cvtpk(bf2f(qv.z & 0xffff) * SCLQ, bf2f(qv.z >> 16) * SCLQ);
    qs.w = cvtpk(bf2f(qv.w & 0xffff) * SCLQ, bf2f(qv.w >> 16) * SCLQ);
    *(uint4*)&q[dst] = qs;
    *(uint4*)&k[dst] = *(const uint4*)&qkv[src + INNERD];
    uint4 vv = *(const uint4*)&qkv[src + 2 * INNERD];
    unsigned short* tr = &t[n][dh0];
    tr[0] = (unsigned short)(vv.x & 0xffff); tr[1] = (unsigned short)(vv.x >> 16);
    tr[2] = (unsigned short)(vv.y & 0xffff); tr[3] = (unsigned short)(vv.y >> 16);
    tr[4] = (unsigned short)(vv.z & 0xffff); tr[5] = (unsigned short)(vv.z >> 16);
    tr[6] = (unsigned short)(vv.w & 0xffff); tr[7] = (unsigned short)(vv.w >> 16);
  }
  __syncthreads();
#pragma unroll
  for (int j = 0; j < 16; ++j) {
    int i = tid + j * 256;
    int dh = i >> 6, n = i & 63;
    vt[((size_t)bh * DHH + dh) * SEQL + n0 + n] = t[n][dh];
  }
  // per-block V column sums -> atomics (divided by SEQL in attn_combine)
  int dh = tid >> 2, seg = tid & 3;
  float s = 0.f;
#pragma unroll
  for (int i = 0; i < 16; ++i) s += bf2f(t[seg * 16 + i][dh]);
  s += __shfl_xor(s, 1);
  s += __shfl_xor(s, 2);
  if (seg == 0) atomicAdd(&vsum[bh * 64 + dh], s);
}

// ---------------- flash attention: 32 q-rows/wave, K/V frags reused across q-halves ----------------
__global__ __launch_bounds__(256, 4)
void attn_split(const unsigned short* __restrict__ qg,
                const unsigned short* __restrict__ kg,
                const unsigned short* __restrict__ vtg,
                const float* __restrict__ maskadd,
                unsigned short* __restrict__ opart,  // [NSPLIT][16][SEQL][DHH] bf16 (unnormalized)
                float* __restrict__ lpart) {        // [NSPLIT][16][SEQL]
  __shared__ __align__(16) unsigned short Ks[64 * 64];
  __shared__ __align__(16) unsigned short Vts[64 * 64];
  __shared__ __align__(16) unsigned short Ps[4 * 32 * 64];
  const int tid = threadIdx.x, w = tid >> 6, lane = tid & 63;
  const int g = lane >> 4, c = lane & 15;
  const int bh = blockIdx.y, b = bh >> 3;
  const int qt = blockIdx.x;          // 16 tiles of 128 q-rows
  const int split = blockIdx.z;
  const int kv0 = split * KPS;
  const int q0 = qt * 128 + w * 32;   // wave owns 32 q-rows
  const float* maskb = maskadd + b * SEQL;

  bf16x8 qf0[2], qf1[2];  // [kb] for q-half 0 (rows c) and 1 (rows 16+c)
#pragma unroll
  for (int kb = 0; kb < 2; ++kb) {
    qf0[kb] = *(const bf16x8*)&qg[((size_t)bh * SEQL + q0 + c) * DHH + kb * 32 + g * 8];
    qf1[kb] = *(const bf16x8*)&qg[((size_t)bh * SEQL + q0 + 16 + c) * DHH + kb * 32 + g * 8];
  }

  const __bf16 one1 = (__bf16)1.0f;
  const bf16x8 ones = {one1, one1, one1, one1, one1, one1, one1, one1};

  f32x4 o0[4] = {}, o1[4] = {};
  f32x4 lones0 = {}, lones1 = {};
  unsigned short* myP = &Ps[w * 2048];

  for (int kt = 0; kt < KPS / 64; ++kt) {
#pragma unroll
    for (int j = 0; j < 2; ++j) {
      int r = w * 16 + j * 8 + (lane >> 3);
      int cl = (lane & 7) ^ (r & 7);
      GLDS16(kg + ((size_t)bh * SEQL + kv0 + kt * 64 + r) * DHH + cl * 8, &Ks[(w * 16 + j * 8) * 64]);
      GLDS16(vtg + ((size_t)bh * DHH + r) * SEQL + kv0 + kt * 64 + cl * 8, &Vts[(w * 16 + j * 8) * 64]);
    }
    __syncthreads();

    // S^T = K @ Q^T + mask (C-init); each K fragment read once, feeds both q-halves
    f32x4 sT0[4], sT1[4];
#pragma unroll
    for (int nt = 0; nt < 4; ++nt) {
      f32x4 mk = *(const f32x4*)&maskb[kv0 + kt * 64 + nt * 16 + g * 4];
      sT0[nt] = mk;
      sT1[nt] = mk;
    }
#pragma unroll
    for (int nt = 0; nt < 4; ++nt) {
#pragma unroll
      for (int kb = 0; kb < 2; ++kb) {
        int kr = nt * 16 + c;
        int cs = (kb * 4 + g) ^ (kr & 7);
        bf16x8 kf = *(const bf16x8*)&Ks[kr * 64 + cs * 8];
        sT0[nt] = __builtin_amdgcn_mfma_f32_16x16x32_bf16(kf, qf0[kb], sT0[nt], 0, 0, 0);
        sT1[nt] = __builtin_amdgcn_mfma_f32_16x16x32_bf16(kf, qf1[kb], sT1[nt], 0, 0, 0);
      }
    }

    // p = exp2(S), pack, write to wave-private LDS rows (fixed m = 0)
#pragma unroll
    for (int nt = 0; nt < 4; ++nt) {
      int swz = (((nt * 2 + (g >> 1)) ^ (c & 7)) << 3) + ((g & 1) << 2);
      {
        float pv0 = exp2f(sT0[nt][0]), pv1 = exp2f(sT0[nt][1]);
        float pv2 = exp2f(sT0[nt][2]), pv3 = exp2f(sT0[nt][3]);
        *(uint2*)(myP + c * 64 + swz) = make_uint2(cvtpk(pv0, pv1), cvtpk(pv2, pv3));
      }
      {
        float pv0 = exp2f(sT1[nt][0]), pv1 = exp2f(sT1[nt][1]);
        float pv2 = exp2f(sT1[nt][2]), pv3 = exp2f(sT1[nt][3]);
        *(uint2*)(myP + (16 + c) * 64 + swz) = make_uint2(cvtpk(pv0, pv1), cvtpk(pv2, pv3));
      }
    }

    // PV + l: each V fragment read once, feeds both q-halves
#pragma unroll
    for (int kb = 0; kb < 2; ++kb) {
      int ps = ((kb * 4 + g) ^ (c & 7)) << 3;
      bf16x8 pf0 = *(const bf16x8*)&myP[c * 64 + ps];
      bf16x8 pf1 = *(const bf16x8*)&myP[(16 + c) * 64 + ps];
      lones0 = __builtin_amdgcn_mfma_f32_16x16x32_bf16(pf0, ones, lones0, 0, 0, 0);
      lones1 = __builtin_amdgcn_mfma_f32_16x16x32_bf16(pf1, ones, lones1, 0, 0, 0);
#pragma unroll
      for (int ni = 0; ni < 4; ++ni) {
        int vr = ni * 16 + c;
        int vc = (kb * 4 + g) ^ (vr & 7);
        bf16x8 vf = *(const bf16x8*)&Vts[vr * 64 + vc * 8];
        o0[ni] = __builtin_amdgcn_mfma_f32_16x16x32_bf16(pf0, vf, o0[ni], 0, 0, 0);
        o1[ni] = __builtin_amdgcn_mfma_f32_16x16x32_bf16(pf1, vf, o1[ni], 0, 0, 0);
      }
    }
    __syncthreads();
  }

  const size_t pb = ((size_t)split * 16 + bh) * SEQL;
#pragma unroll
  for (int ni = 0; ni < 4; ++ni) {
#pragma unroll
    for (int r = 0; r < 4; ++r) {
      opart[(pb + q0 + g * 4 + r) * DHH + ni * 16 + c] = f2bf(o0[ni][r]);
      opart[(pb + q0 + 16 + g * 4 + r) * DHH + ni * 16 + c] = f2bf(o1[ni][r]);
    }
  }
  if (c == 0) {
#pragma unroll
    for (int r = 0; r < 4; ++r) {
      lpart[pb + q0 + g * 4 + r] = lones0[r];
      lpart[pb + q0 + 16 + g * 4 + r] = lones1[r];
    }
  }
}

__global__ __launch_bounds__(256) void attn_combine(const unsigned short* __restrict__ opart,
                                                    const float* __restrict__ lpart,
                                                    const float* __restrict__ maskadd,
                                                    const float* __restrict__ vsum,
                                                    unsigned short* __restrict__ ctx) {
  int idx = blockIdx.x * 256 + threadIdx.x;  // 16*SEQL*16 threads, 4 d each
  int dq = idx & 15;
  int q = (idx >> 4) & (SEQL - 1);
  int bh = idx >> 15;
  int d0 = dq * 4;
  int b = bh >> 3, h = bh & 7;
  float o0 = 0.f, o1 = 0.f, o2 = 0.f, o3 = 0.f, L = 0.f;
#pragma unroll
  for (int s = 0; s < NSPLIT; ++s) {
    size_t base = ((size_t)s * 16 + bh) * SEQL + q;
    L += lpart[base];
    uint2 v = *(const uint2*)&opart[base * DHH + d0];
    o0 += bf2f(v.x & 0xffff); o1 += bf2f(v.x >> 16);
    o2 += bf2f(v.y & 0xffff); o3 += bf2f(v.y >> 16);
  }
  float r = 1.0f / L;
  o0 *= r; o1 *= r; o2 *= r; o3 *= r;
  if (maskadd[b * SEQL + q] != 0.f) {  // masked q: reference gives uniform attention = mean(V)
    f32x4 vm = *(const f32x4*)&vsum[bh * 64 + d0];
    o0 = vm[0] * (1.0f / SEQL); o1 = vm[1] * (1.0f / SEQL);
    o2 = vm[2] * (1.0f / SEQL); o3 = vm[3] * (1.0f / SEQL);
  }
  *(uint2*)&ctx[((size_t)(b * SEQL + q)) * INNERD + h * 64 + d0] =
      make_uint2(cvtpk(o0, o1), cvtpk(o2, o3));
}

// ---------------- host ----------------
extern "C" void kernel_launch(void* const* d_in, const int* in_sizes, int n_in,
                              void* d_out, int out_size, void* d_ws, size_t ws_size,
                              hipStream_t stream) {
  (void)in_sizes; (void)n_in; (void)out_size;
  const float* x_in = (const float*)d_in[0];
  const int* mask = (const int*)d_in[1];
  const float* qkv_w = (const float*)d_in[2];
  const float* out_w = (const float*)d_in[3];
  const float* out_b = (const float*)d_in[4];
  const float* ff_w1 = (const float*)d_in[5];
  const float* ff_b1 = (const float*)d_in[6];
  const float* ff_w2 = (const float*)d_in[7];
  const float* ff_b2 = (const float*)d_in[8];
  const float* ad1w = (const float*)d_in[9];
  const float* ad1b = (const float*)d_in[10];
  const float* ad2w = (const float*)d_in[11];
  const float* ad2b = (const float*)d_in[12];

  char* ws = (char*)d_ws;
  size_t off = 0;
  auto alloc = [&](size_t bytes) {
    char* p = ws + off;
    off = (off + bytes + 255) & ~(size_t)255;
    return p;
  };
  unsigned short* wtQ = (unsigned short*)alloc((size_t)DEPTHL * 1536 * 512 * 2);
  unsigned short* wtO = (unsigned short*)alloc((size_t)DEPTHL * 512 * 512 * 2);
  unsigned short* wtF1 = (unsigned short*)alloc((size_t)DEPTHL * 2048 * 512 * 2);
  unsigned short* wtF2 = (unsigned short*)alloc((size_t)DEPTHL * 512 * 2048 * 2);
  float* xc = (float*)alloc((size_t)ROWS * DIMM * 4);
  unsigned short* hbf = (unsigned short*)alloc((size_t)ROWS * DIMM * 2);
  unsigned short* qkvbf = (unsigned short*)alloc((size_t)ROWS * 1536 * 2);
  char* region2 = alloc((size_t)4 * 16 * SEQL * DHH * 2);  // q,k,vt,ctx OR h1
  unsigned short* qb = (unsigned short*)region2;
  unsigned short* kb = qb + (size_t)16 * SEQL * DHH;
  unsigned short* vtb = kb + (size_t)16 * SEQL * DHH;
  unsigned short* ctxb = vtb + (size_t)16 * SEQL * DHH;
  unsigned short* h1bf = (unsigned short*)region2;  // aliases q/k/vt/ctx (disjoint lifetime)
  float* p1 = (float*)alloc((size_t)BB * 32 * DIMM * 4);
  float* p2 = (float*)alloc((size_t)BB * 32 * DIMM * 4);
  float* alpha = (float*)alloc((size_t)BB * DIMM * 4);
  float* beta = (float*)alloc((size_t)BB * DIMM * 4);
  float* maskadd = (float*)alloc((size_t)BB * SEQL * 4);
  unsigned short* opart = (unsigned short*)alloc((size_t)NSPLIT * 16 * SEQL * DHH * 2);
  float* lpart = (float*)alloc((size_t)NSPLIT * 16 * SEQL * 4);
  float* vsum = (float*)alloc((size_t)16 * 64 * 4);
  unsigned short* part = (unsigned short*)alloc((size_t)4 * ROWS * 512 * 2);  // 16MB bf16 split-K partials
  const bool fits = off <= ws_size;  // graceful fallback if workspace too small

  // x working copy
  hipMemcpyAsync(xc, x_in, (size_t)ROWS * DIMM * 4, hipMemcpyDeviceToDevice, stream);

  // weights -> bf16 transposed [N][K]
  wtrans<<<dim3(512 / 32, 1536 / 32, DEPTHL), 256, 0, stream>>>(qkv_w, wtQ, 512, 1536);
  wtrans<<<dim3(512 / 32, 512 / 32, DEPTHL), 256, 0, stream>>>(out_w, wtO, 512, 512);
  wtrans<<<dim3(512 / 32, 2048 / 32, DEPTHL), 256, 0, stream>>>(ff_w1, wtF1, 512, 2048);
  wtrans<<<dim3(2048 / 32, 512 / 32, DEPTHL), 256, 0, stream>>>(ff_w2, wtF2, 2048, 512);
  maskbuild<<<BB * SEQL / 256, 256, 0, stream>>>(mask, maskadd);

  for (int l = 0; l < DEPTHL; ++l) {
    // adain 1
    adain_p1<<<dim3(32, BB), 512, 0, stream>>>(xc, p1, p2);
    adain_p2<<<BB, 512, 0, stream>>>(p1, p2, ad1w + l * BB * DIMM, ad1b + l * BB * DIMM, alpha, beta);
    adain_apply<<<8192, 256, 0, stream>>>(xc, alpha, beta, hbf);
    // qkv: [4096,512] x [512,1536] -> bf16
    gemm_k<0, 64><<<dim3(1536 / 64, ROWS / 128), 256, 0, stream>>>(
        hbf, wtQ + (size_t)l * 1536 * 512, nullptr, nullptr, nullptr, qkvbf, nullptr, 1536, 512);
    hipMemsetAsync(vsum, 0, 16 * 64 * 4, stream);
    qkv_prep<<<dim3(16, 32), 256, 0, stream>>>(qkvbf, qb, kb, vtb, vsum);
    attn_split<<<dim3(SEQL / 128, 16, NSPLIT), 256, 0, stream>>>(qb, kb, vtb, maskadd, opart, lpart);
    attn_combine<<<16 * SEQL * 16 / 256, 256, 0, stream>>>(opart, lpart, maskadd, vsum, ctxb);
    // out proj + residual (in place on xc)
    if (fits) {
      gemm_k<3, 64><<<dim3(512 / 64, ROWS / 128, 2), 256, 0, stream>>>(
          ctxb, wtO + (size_t)l * 512 * 512, nullptr, nullptr, nullptr, nullptr, part, 512, 512);
      comb_k<2><<<ROWS * 512 / 1024, 256, 0, stream>>>(part, out_b + l * DIMM, xc, xc);
    } else {
      gemm_k<2, 64><<<dim3(512 / 64, ROWS / 128), 256, 0, stream>>>(
          ctxb, wtO + (size_t)l * 512 * 512, out_b + l * DIMM, xc, xc, nullptr, nullptr, 512, 512);
    }
    // adain 2
    adain_p1<<<dim3(32, BB), 512, 0, stream>>>(xc, p1, p2);
    adain_p2<<<BB, 512, 0, stream>>>(p1, p2, ad2w + l * BB * DIMM, ad2b + l * BB * DIMM, alpha, beta);
    adain_apply<<<8192, 256, 0, stream>>>(xc, alpha, beta, hbf);
    // ff1 (gelu) -> h1
    gemm_k<1, 64><<<dim3(2048 / 64, ROWS / 128), 256, 0, stream>>>(
        hbf, wtF1 + (size_t)l * 2048 * 512, ff_b1 + l * MLPD, nullptr, nullptr, h1bf, nullptr, 2048, 512);
    // ff2 + residual
    float* xout = (l == DEPTHL - 1) ? (float*)d_out : xc;
    if (fits) {
      gemm_k<3, 64><<<dim3(512 / 64, ROWS / 128, 4), 256, 0, stream>>>(
          h1bf, wtF2 + (size_t)l * 512 * 2048, nullptr, nullptr, nullptr, nullptr, part, 512, 2048);
      comb_k<4><<<ROWS * 512 / 1024, 256, 0, stream>>>(part, ff_b2 + l * DIMM, xc, xout);
    } else {
      gemm_k<2, 64><<<dim3(512 / 64, ROWS / 128), 256, 0, stream>>>(
          h1bf, wtF2 + (size_t)l * 512 * 2048, ff_b2 + l * DIMM, xc, xout, nullptr, nullptr, 512, 2048);
    }
  }
}

// Round 10
// 284.976 us; speedup vs baseline: 1.1833x; 1.0968x over previous
//
#include <hip/hip_runtime.h>
#include <hip/hip_bf16.h>

#define DEPTHL 2
#define DIMM   512
#define NHEADS 8
#define DHH    64
#define INNERD 512
#define MLPD   2048
#define BB     2
#define SEQL   2048
#define ROWS   (BB*SEQL)
#define MNEG   (-1.0e38f)
#define SCLQ   0.18033688f   /* 0.125 * log2(e), folded into Q */
#define NSPLIT 4
#define KPS    (SEQL / NSPLIT)
#define NCH    128

typedef __attribute__((ext_vector_type(4))) float f32x4;
typedef __attribute__((ext_vector_type(8))) __bf16 bf16x8;

#define GLDS16(g, l) __builtin_amdgcn_global_load_lds((const __attribute__((address_space(1))) void*)(g), (__attribute__((address_space(3))) void*)(l), 16, 0, 0)

__device__ __forceinline__ unsigned short f2bf(float f) {
  union { float f; unsigned int u; } v; v.f = f;
  unsigned int r = v.u + 0x7fffu + ((v.u >> 16) & 1u);
  return (unsigned short)(r >> 16);
}
__device__ __forceinline__ float bf2f(unsigned short h) {
  union { unsigned int u; float f; } v; v.u = ((unsigned int)h) << 16; return v.f;
}
__device__ __forceinline__ unsigned int cvtpk(float a, float b) {
  unsigned int r;
  asm("v_cvt_pk_bf16_f32 %0, %1, %2" : "=v"(r) : "v"(a), "v"(b));
  return r;
}

// ---------------- weight transpose fp32[K][N] -> bf16[N][K] ----------------
__global__ __launch_bounds__(256) void wtrans(const float* __restrict__ wsrc,
                                              unsigned short* __restrict__ wdst,
                                              int K, int N) {
  __shared__ float t[32][33];
  const float* src = wsrc + (size_t)blockIdx.z * K * N;
  unsigned short* dst = wdst + (size_t)blockIdx.z * K * N;
  int k0 = blockIdx.x * 32, n0 = blockIdx.y * 32;
  int tx = threadIdx.x & 31, ty = threadIdx.x >> 5;  // 32x8
#pragma unroll
  for (int j = 0; j < 32; j += 8)
    t[ty + j][tx] = src[(size_t)(k0 + ty + j) * N + n0 + tx];
  __syncthreads();
#pragma unroll
  for (int j = 0; j < 32; j += 8)
    dst[(size_t)(n0 + ty + j) * K + k0 + tx] = f2bf(t[tx][ty + j]);
}

// ---------------- adain: p1 (128 chunks x 16 rows), p2 (parallel reduce), apply (x4 vec) ----------------
__global__ __launch_bounds__(512) void adain_p1(const float* __restrict__ x,
                                                float* __restrict__ p1, float* __restrict__ p2) {
  int d = threadIdx.x, c = blockIdx.x, b = blockIdx.y;
  const float* xp = x + ((size_t)b * SEQL + c * 16) * DIMM + d;
  float s = 0.f, s2 = 0.f;
#pragma unroll
  for (int i = 0; i < 16; ++i) { float v = xp[(size_t)i * DIMM]; s += v; s2 += v * v; }
  p1[(b * NCH + c) * DIMM + d] = s;
  p2[(b * NCH + c) * DIMM + d] = s2;
}

__global__ __launch_bounds__(512) void adain_p2(const float* __restrict__ p1, const float* __restrict__ p2,
                                                const float* __restrict__ w, const float* __restrict__ bi,
                                                float* __restrict__ alpha, float* __restrict__ beta) {
  __shared__ float redA[8][64], redB[8][64];
  int b = blockIdx.x, dg = blockIdx.y;
  int dl = threadIdx.x & 63, seg = threadIdx.x >> 6;
  int d = dg * 64 + dl;
  float s = 0.f, s2 = 0.f;
#pragma unroll
  for (int i = 0; i < 16; ++i) {
    int c = seg * 16 + i;
    s += p1[(b * NCH + c) * DIMM + d];
    s2 += p2[(b * NCH + c) * DIMM + d];
  }
  redA[seg][dl] = s; redB[seg][dl] = s2;
  __syncthreads();
  if (seg == 0) {
#pragma unroll
    for (int i = 1; i < 8; ++i) { s += redA[i][dl]; s2 += redB[i][dl]; }
    float mean = s * (1.0f / SEQL);
    float var = s2 * (1.0f / SEQL) - mean * mean;
    float a = w[b * DIMM + d] * rsqrtf(var + 1e-6f);
    alpha[b * DIMM + d] = a;
    beta[b * DIMM + d] = bi[b * DIMM + d] - mean * a;
  }
}

__global__ __launch_bounds__(256) void adain_apply(const float* __restrict__ x,
                                                   const float* __restrict__ alpha, const float* __restrict__ beta,
                                                   unsigned short* __restrict__ hb) {
  int idx = (blockIdx.x * 256 + threadIdx.x) * 4;  // over ROWS*DIMM = 2^21
  int d = idx & (DIMM - 1);
  int b = idx >> 20;
  f32x4 xv = *(const f32x4*)&x[idx];
  f32x4 av = *(const f32x4*)&alpha[b * DIMM + d];
  f32x4 bv = *(const f32x4*)&beta[b * DIMM + d];
  *(uint2*)&hb[idx] = make_uint2(cvtpk(xv[0] * av[0] + bv[0], xv[1] * av[1] + bv[1]),
                                 cvtpk(xv[2] * av[2] + bv[2], xv[3] * av[3] + bv[3]));
}

// ---------------- mask -> additive float (0 or -1e38) ----------------
__global__ __launch_bounds__(256) void maskbuild(const int* __restrict__ mask, float* __restrict__ maskadd) {
  int i = blockIdx.x * 256 + threadIdx.x;  // B*N = 4096
  maskadd[i] = mask[i] ? 0.f : MNEG;
}

// ---------------- GEMM: out = A[M,Kt](bf16) @ Wt[N,Kt]^T(bf16) ----------------
// EPI: 0 = bf16 out, 1 = gelu->bf16 out, 2 = fp32 out + bias + resid, 3 = bf16 partial (split-K),
//      4 = fused qkv scatter (q scaled, k, v transposed)
template <int EPI, int BN>
__global__ __launch_bounds__(256)
void gemm_k(const unsigned short* __restrict__ A,
            const unsigned short* __restrict__ Wt,
            const float* __restrict__ bias,
            const float* __restrict__ resid,
            float* __restrict__ outF,
            unsigned short* __restrict__ outB,
            unsigned short* __restrict__ part,
            unsigned short* __restrict__ qg4,
            unsigned short* __restrict__ kg4,
            unsigned short* __restrict__ vt4,
            int N, int Kt) {
  constexpr int NI = BN / 32;
  __shared__ __align__(16) unsigned short As[2][128 * 32];
  __shared__ __align__(16) unsigned short Bs[2][BN * 32];
  const int tid = threadIdx.x;
  const int w = tid >> 6, lane = tid & 63;

  unsigned int f = blockIdx.y * gridDim.x + blockIdx.x;
  unsigned int grp = f & 7u, idx = f >> 3;
  unsigned int rpx = gridDim.y >> 3;
  unsigned int by = grp * rpx + idx / gridDim.x;
  unsigned int bx = idx % gridDim.x;

  const int bm = by * 128, bn = bx * BN;
  const int wm = (w >> 1) * 64, wn = (w & 1) * (BN / 2);

  const int nsplit = gridDim.z, sp = blockIdx.z;
  const int Kc = Kt / nsplit;
  const int kbeg = sp * Kc, kend = kbeg + Kc;

  f32x4 acc[4][NI] = {};

  auto stage = [&](int buf, int k0) {
#pragma unroll
    for (int j = 0; j < 2; ++j) {
      int r = w * 32 + (lane >> 2) + j * 16;
      int cl = (lane & 3) ^ ((r >> 1) & 3);
      GLDS16(A + (size_t)(bm + r) * Kt + k0 + cl * 8, &As[buf][(w * 32 + j * 16) * 32]);
    }
    if (BN == 128) {
#pragma unroll
      for (int j = 0; j < 2; ++j) {
        int r = w * 32 + (lane >> 2) + j * 16;
        int cl = (lane & 3) ^ ((r >> 1) & 3);
        GLDS16(Wt + (size_t)(bn + r) * Kt + k0 + cl * 8, &Bs[buf][(w * 32 + j * 16) * 32]);
      }
    } else {
      int r = w * 16 + (lane >> 2);
      int cl = (lane & 3) ^ ((r >> 1) & 3);
      GLDS16(Wt + (size_t)(bn + r) * Kt + k0 + cl * 8, &Bs[buf][(w * 16) * 32]);
    }
  };

  stage(0, kbeg);
  __syncthreads();
  int cur = 0;

  for (int k0 = kbeg; k0 < kend; k0 += 32) {
    if (k0 + 32 < kend) stage(cur ^ 1, k0 + 32);
    bf16x8 af[4], bfr[NI];
#pragma unroll
    for (int i = 0; i < 4; ++i) {
      int ar = wm + i * 16 + (lane & 15);
      int ac = (lane >> 4) ^ ((ar >> 1) & 3);
      af[i] = *(const bf16x8*)&As[cur][ar * 32 + ac * 8];
    }
#pragma unroll
    for (int i = 0; i < NI; ++i) {
      int br = wn + i * 16 + (lane & 15);
      int bc = (lane >> 4) ^ ((br >> 1) & 3);
      bfr[i] = *(const bf16x8*)&Bs[cur][br * 32 + bc * 8];
    }
#pragma unroll
    for (int mi = 0; mi < 4; ++mi)
#pragma unroll
      for (int ni = 0; ni < NI; ++ni)
        acc[mi][ni] = __builtin_amdgcn_mfma_f32_16x16x32_bf16(af[mi], bfr[ni], acc[mi][ni], 0, 0, 0);
    __syncthreads();
    cur ^= 1;
  }

  const size_t MN = (size_t)gridDim.y * 128 * N;
#pragma unroll
  for (int mi = 0; mi < 4; ++mi) {
#pragma unroll
    for (int ni = 0; ni < NI; ++ni) {
#pragma unroll
      for (int r = 0; r < 4; ++r) {
        int row = bm + wm + mi * 16 + (lane >> 4) * 4 + r;
        int col = bn + wn + ni * 16 + (lane & 15);
        float v = acc[mi][ni][r];
        if (EPI == 4) {
          int brow = row >> 11, n = row & (SEQL - 1);
          int sec = col >> 9, h = (col >> 6) & 7, dh = col & 63;
          int bh = brow * 8 + h;
          if (sec == 0) qg4[((size_t)bh * SEQL + n) * DHH + dh] = f2bf(v * SCLQ);
          else if (sec == 1) kg4[((size_t)bh * SEQL + n) * DHH + dh] = f2bf(v);
          else vt4[((size_t)bh * DHH + dh) * SEQL + n] = f2bf(v);
        } else {
          size_t o = (size_t)row * N + col;
          if (EPI == 3) {
            part[(size_t)sp * MN + o] = f2bf(v);
          } else {
            if (bias) v += bias[col];
            if (EPI == 1) v = 0.5f * v * (1.0f + erff(v * 0.70710678118f));
            if (EPI == 2) outF[o] = v + resid[o];
            else outB[o] = f2bf(v);
          }
        }
      }
    }
  }
}

// ---------------- split-K combine (bf16 partials): out = sum(part) + bias + resid ----------------
template <int NS>
__global__ __launch_bounds__(256) void comb_k(const unsigned short* __restrict__ part,
                                              const float* __restrict__ bias,
                                              const float* __restrict__ resid,
                                              float* __restrict__ outF) {
  size_t idx = ((size_t)blockIdx.x * 256 + threadIdx.x) * 4;  // over ROWS*512
  int col = (int)(idx & 511);
  float a0 = 0.f, a1 = 0.f, a2 = 0.f, a3 = 0.f;
#pragma unroll
  for (int s = 0; s < NS; ++s) {
    uint2 v = *(const uint2*)&part[(size_t)s * ROWS * 512 + idx];
    a0 += bf2f(v.x & 0xffff); a1 += bf2f(v.x >> 16);
    a2 += bf2f(v.y & 0xffff); a3 += bf2f(v.y >> 16);
  }
  f32x4 b = *(const f32x4*)&bias[col];
  f32x4 rs = *(const f32x4*)&resid[idx];
  f32x4 o;
  o[0] = a0 + b[0] + rs[0]; o[1] = a1 + b[1] + rs[1];
  o[2] = a2 + b[2] + rs[2]; o[3] = a3 + b[3] + rs[3];
  *(f32x4*)&outF[idx] = o;
}

// ---------------- V column means (direct write, no atomics) ----------------
__global__ __launch_bounds__(256) void vmean_k(const unsigned short* __restrict__ vt,
                                               float* __restrict__ vmean) {
  __shared__ float red[256];
  int bh = blockIdx.x, t = threadIdx.x;
  int d = blockIdx.y * 8 + (t >> 5), seg = t & 31;
  const unsigned short* p = vt + ((size_t)bh * 64 + d) * SEQL + seg * 64;
  float s = 0.f;
#pragma unroll
  for (int i = 0; i < 16; ++i) {
    uint2 v = *(const uint2*)&p[i * 4];
    s += bf2f(v.x & 0xffff) + bf2f(v.x >> 16) + bf2f(v.y & 0xffff) + bf2f(v.y >> 16);
  }
  red[t] = s;
  __syncthreads();
  if (t < 8) {
    float a = 0.f;
#pragma unroll
    for (int i = 0; i < 32; ++i) a += red[t * 32 + i];
    vmean[bh * 64 + blockIdx.y * 8 + t] = a * (1.0f / SEQL);
  }
}

// ---------------- flash attention: 32 q-rows/wave, K/V frags reused across q-halves ----------------
__global__ __launch_bounds__(256, 4)
void attn_split(const unsigned short* __restrict__ qg,
                const unsigned short* __restrict__ kg,
                const unsigned short* __restrict__ vtg,
                const float* __restrict__ maskadd,
                unsigned short* __restrict__ opart,
                float* __restrict__ lpart) {
  __shared__ __align__(16) unsigned short Ks[64 * 64];
  __shared__ __align__(16) unsigned short Vts[64 * 64];
  __shared__ __align__(16) unsigned short Ps[4 * 32 * 64];
  const int tid = threadIdx.x, w = tid >> 6, lane = tid & 63;
  const int g = lane >> 4, c = lane & 15;
  const int bh = blockIdx.y, b = bh >> 3;
  const int qt = blockIdx.x;
  const int split = blockIdx.z;
  const int kv0 = split * KPS;
  const int q0 = qt * 128 + w * 32;
  const float* maskb = maskadd + b * SEQL;

  bf16x8 qf0[2], qf1[2];
#pragma unroll
  for (int kb = 0; kb < 2; ++kb) {
    qf0[kb] = *(const bf16x8*)&qg[((size_t)bh * SEQL + q0 + c) * DHH + kb * 32 + g * 8];
    qf1[kb] = *(const bf16x8*)&qg[((size_t)bh * SEQL + q0 + 16 + c) * DHH + kb * 32 + g * 8];
  }

  const __bf16 one1 = (__bf16)1.0f;
  const bf16x8 ones = {one1, one1, one1, one1, one1, one1, one1, one1};

  f32x4 o0[4] = {}, o1[4] = {};
  f32x4 lones0 = {}, lones1 = {};
  unsigned short* myP = &Ps[w * 2048];

  for (int kt = 0; kt < KPS / 64; ++kt) {
#pragma unroll
    for (int j = 0; j < 2; ++j) {
      int r = w * 16 + j * 8 + (lane >> 3);
      int cl = (lane & 7) ^ (r & 7);
      GLDS16(kg + ((size_t)bh * SEQL + kv0 + kt * 64 + r) * DHH + cl * 8, &Ks[(w * 16 + j * 8) * 64]);
      GLDS16(vtg + ((size_t)bh * DHH + r) * SEQL + kv0 + kt * 64 + cl * 8, &Vts[(w * 16 + j * 8) * 64]);
    }
    __syncthreads();

    f32x4 sT0[4], sT1[4];
#pragma unroll
    for (int nt = 0; nt < 4; ++nt) {
      f32x4 mk = *(const f32x4*)&maskb[kv0 + kt * 64 + nt * 16 + g * 4];
      sT0[nt] = mk;
      sT1[nt] = mk;
    }
#pragma unroll
    for (int nt = 0; nt < 4; ++nt) {
#pragma unroll
      for (int kb = 0; kb < 2; ++kb) {
        int kr = nt * 16 + c;
        int cs = (kb * 4 + g) ^ (kr & 7);
        bf16x8 kf = *(const bf16x8*)&Ks[kr * 64 + cs * 8];
        sT0[nt] = __builtin_amdgcn_mfma_f32_16x16x32_bf16(kf, qf0[kb], sT0[nt], 0, 0, 0);
        sT1[nt] = __builtin_amdgcn_mfma_f32_16x16x32_bf16(kf, qf1[kb], sT1[nt], 0, 0, 0);
      }
    }

#pragma unroll
    for (int nt = 0; nt < 4; ++nt) {
      int swz = (((nt * 2 + (g >> 1)) ^ (c & 7)) << 3) + ((g & 1) << 2);
      {
        float pv0 = exp2f(sT0[nt][0]), pv1 = exp2f(sT0[nt][1]);
        float pv2 = exp2f(sT0[nt][2]), pv3 = exp2f(sT0[nt][3]);
        *(uint2*)(myP + c * 64 + swz) = make_uint2(cvtpk(pv0, pv1), cvtpk(pv2, pv3));
      }
      {
        float pv0 = exp2f(sT1[nt][0]), pv1 = exp2f(sT1[nt][1]);
        float pv2 = exp2f(sT1[nt][2]), pv3 = exp2f(sT1[nt][3]);
        *(uint2*)(myP + (16 + c) * 64 + swz) = make_uint2(cvtpk(pv0, pv1), cvtpk(pv2, pv3));
      }
    }

#pragma unroll
    for (int kb = 0; kb < 2; ++kb) {
      int ps = ((kb * 4 + g) ^ (c & 7)) << 3;
      bf16x8 pf0 = *(const bf16x8*)&myP[c * 64 + ps];
      bf16x8 pf1 = *(const bf16x8*)&myP[(16 + c) * 64 + ps];
      lones0 = __builtin_amdgcn_mfma_f32_16x16x32_bf16(pf0, ones, lones0, 0, 0, 0);
      lones1 = __builtin_amdgcn_mfma_f32_16x16x32_bf16(pf1, ones, lones1, 0, 0, 0);
#pragma unroll
      for (int ni = 0; ni < 4; ++ni) {
        int vr = ni * 16 + c;
        int vc = (kb * 4 + g) ^ (vr & 7);
        bf16x8 vf = *(const bf16x8*)&Vts[vr * 64 + vc * 8];
        o0[ni] = __builtin_amdgcn_mfma_f32_16x16x32_bf16(pf0, vf, o0[ni], 0, 0, 0);
        o1[ni] = __builtin_amdgcn_mfma_f32_16x16x32_bf16(pf1, vf, o1[ni], 0, 0, 0);
      }
    }
    __syncthreads();
  }

  const size_t pb = ((size_t)split * 16 + bh) * SEQL;
#pragma unroll
  for (int ni = 0; ni < 4; ++ni) {
#pragma unroll
    for (int r = 0; r < 4; ++r) {
      opart[(pb + q0 + g * 4 + r) * DHH + ni * 16 + c] = f2bf(o0[ni][r]);
      opart[(pb + q0 + 16 + g * 4 + r) * DHH + ni * 16 + c] = f2bf(o1[ni][r]);
    }
  }
  if (c == 0) {
#pragma unroll
    for (int r = 0; r < 4; ++r) {
      lpart[pb + q0 + g * 4 + r] = lones0[r];
      lpart[pb + q0 + 16 + g * 4 + r] = lones1[r];
    }
  }
}

__global__ __launch_bounds__(256) void attn_combine(const unsigned short* __restrict__ opart,
                                                    const float* __restrict__ lpart,
                                                    const float* __restrict__ maskadd,
                                                    const float* __restrict__ vmean,
                                                    unsigned short* __restrict__ ctx) {
  int idx = blockIdx.x * 256 + threadIdx.x;
  int dq = idx & 15;
  int q = (idx >> 4) & (SEQL - 1);
  int bh = idx >> 15;
  int d0 = dq * 4;
  int b = bh >> 3, h = bh & 7;
  float o0 = 0.f, o1 = 0.f, o2 = 0.f, o3 = 0.f, L = 0.f;
#pragma unroll
  for (int s = 0; s < NSPLIT; ++s) {
    size_t base = ((size_t)s * 16 + bh) * SEQL + q;
    L += lpart[base];
    uint2 v = *(const uint2*)&opart[base * DHH + d0];
    o0 += bf2f(v.x & 0xffff); o1 += bf2f(v.x >> 16);
    o2 += bf2f(v.y & 0xffff); o3 += bf2f(v.y >> 16);
  }
  float r = 1.0f / L;
  o0 *= r; o1 *= r; o2 *= r; o3 *= r;
  if (maskadd[b * SEQL + q] != 0.f) {
    f32x4 vm = *(const f32x4*)&vmean[bh * 64 + d0];
    o0 = vm[0]; o1 = vm[1]; o2 = vm[2]; o3 = vm[3];
  }
  *(uint2*)&ctx[((size_t)(b * SEQL + q)) * INNERD + h * 64 + d0] =
      make_uint2(cvtpk(o0, o1), cvtpk(o2, o3));
}

// ---------------- host ----------------
extern "C" void kernel_launch(void* const* d_in, const int* in_sizes, int n_in,
                              void* d_out, int out_size, void* d_ws, size_t ws_size,
                              hipStream_t stream) {
  (void)in_sizes; (void)n_in; (void)out_size;
  const float* x_in = (const float*)d_in[0];
  const int* mask = (const int*)d_in[1];
  const float* qkv_w = (const float*)d_in[2];
  const float* out_w = (const float*)d_in[3];
  const float* out_b = (const float*)d_in[4];
  const float* ff_w1 = (const float*)d_in[5];
  const float* ff_b1 = (const float*)d_in[6];
  const float* ff_w2 = (const float*)d_in[7];
  const float* ff_b2 = (const float*)d_in[8];
  const float* ad1w = (const float*)d_in[9];
  const float* ad1b = (const float*)d_in[10];
  const float* ad2w = (const float*)d_in[11];
  const float* ad2b = (const float*)d_in[12];

  char* ws = (char*)d_ws;
  size_t off = 0;
  auto alloc = [&](size_t bytes) {
    char* p = ws + off;
    off = (off + bytes + 255) & ~(size_t)255;
    return p;
  };
  unsigned short* wtQ = (unsigned short*)alloc((size_t)DEPTHL * 1536 * 512 * 2);
  unsigned short* wtO = (unsigned short*)alloc((size_t)DEPTHL * 512 * 512 * 2);
  unsigned short* wtF1 = (unsigned short*)alloc((size_t)DEPTHL * 2048 * 512 * 2);
  unsigned short* wtF2 = (unsigned short*)alloc((size_t)DEPTHL * 512 * 2048 * 2);
  float* xc = (float*)alloc((size_t)ROWS * DIMM * 4);
  unsigned short* hbf = (unsigned short*)alloc((size_t)ROWS * DIMM * 2);
  char* region2 = alloc((size_t)4 * 16 * SEQL * DHH * 2);  // q,k,vt,ctx OR h1
  unsigned short* qb = (unsigned short*)region2;
  unsigned short* kb = qb + (size_t)16 * SEQL * DHH;
  unsigned short* vtb = kb + (size_t)16 * SEQL * DHH;
  unsigned short* ctxb = vtb + (size_t)16 * SEQL * DHH;
  unsigned short* h1bf = (unsigned short*)region2;  // aliases q/k/vt/ctx (disjoint lifetime)
  float* p1 = (float*)alloc((size_t)BB * NCH * DIMM * 4);
  float* p2 = (float*)alloc((size_t)BB * NCH * DIMM * 4);
  float* alpha = (float*)alloc((size_t)BB * DIMM * 4);
  float* beta = (float*)alloc((size_t)BB * DIMM * 4);
  float* maskadd = (float*)alloc((size_t)BB * SEQL * 4);
  unsigned short* opart = (unsigned short*)alloc((size_t)NSPLIT * 16 * SEQL * DHH * 2);
  float* lpart = (float*)alloc((size_t)NSPLIT * 16 * SEQL * 4);
  float* vmean = (float*)alloc((size_t)16 * 64 * 4);
  unsigned short* part = (unsigned short*)alloc((size_t)4 * ROWS * 512 * 2);
  const bool fits = off <= ws_size;

  // weights -> bf16 transposed [N][K]
  wtrans<<<dim3(512 / 32, 1536 / 32, DEPTHL), 256, 0, stream>>>(qkv_w, wtQ, 512, 1536);
  wtrans<<<dim3(512 / 32, 512 / 32, DEPTHL), 256, 0, stream>>>(out_w, wtO, 512, 512);
  wtrans<<<dim3(512 / 32, 2048 / 32, DEPTHL), 256, 0, stream>>>(ff_w1, wtF1, 512, 2048);
  wtrans<<<dim3(2048 / 32, 512 / 32, DEPTHL), 256, 0, stream>>>(ff_w2, wtF2, 2048, 512);
  maskbuild<<<BB * SEQL / 256, 256, 0, stream>>>(mask, maskadd);

  for (int l = 0; l < DEPTHL; ++l) {
    const float* xr = (l == 0) ? x_in : xc;  // residual stream source this layer
    // adain 1
    adain_p1<<<dim3(NCH, BB), 512, 0, stream>>>(xr, p1, p2);
    adain_p2<<<dim3(BB, 8), 512, 0, stream>>>(p1, p2, ad1w + l * BB * DIMM, ad1b + l * BB * DIMM, alpha, beta);
    adain_apply<<<2048, 256, 0, stream>>>(xr, alpha, beta, hbf);
    // qkv gemm with fused repack epilogue (q scaled, k, v transposed)
    gemm_k<4, 64><<<dim3(1536 / 64, ROWS / 128), 256, 0, stream>>>(
        hbf, wtQ + (size_t)l * 1536 * 512, nullptr, nullptr, nullptr, nullptr, nullptr,
        qb, kb, vtb, 1536, 512);
    vmean_k<<<dim3(16, 8), 256, 0, stream>>>(vtb, vmean);
    attn_split<<<dim3(SEQL / 128, 16, NSPLIT), 256, 0, stream>>>(qb, kb, vtb, maskadd, opart, lpart);
    attn_combine<<<16 * SEQL * 16 / 256, 256, 0, stream>>>(opart, lpart, maskadd, vmean, ctxb);
    // out proj + residual -> xc
    if (fits) {
      gemm_k<3, 64><<<dim3(512 / 64, ROWS / 128, 2), 256, 0, stream>>>(
          ctxb, wtO + (size_t)l * 512 * 512, nullptr, nullptr, nullptr, nullptr, part,
          nullptr, nullptr, nullptr, 512, 512);
      comb_k<2><<<ROWS * 512 / 1024, 256, 0, stream>>>(part, out_b + l * DIMM, xr, xc);
    } else {
      gemm_k<2, 64><<<dim3(512 / 64, ROWS / 128), 256, 0, stream>>>(
          ctxb, wtO + (size_t)l * 512 * 512, out_b + l * DIMM, xr, xc, nullptr, nullptr,
          nullptr, nullptr, nullptr, 512, 512);
    }
    // adain 2
    adain_p1<<<dim3(NCH, BB), 512, 0, stream>>>(xc, p1, p2);
    adain_p2<<<dim3(BB, 8), 512, 0, stream>>>(p1, p2, ad2w + l * BB * DIMM, ad2b + l * BB * DIMM, alpha, beta);
    adain_apply<<<2048, 256, 0, stream>>>(xc, alpha, beta, hbf);
    // ff1 (gelu) -> h1
    gemm_k<1, 64><<<dim3(2048 / 64, ROWS / 128), 256, 0, stream>>>(
        hbf, wtF1 + (size_t)l * 2048 * 512, ff_b1 + l * MLPD, nullptr, nullptr, h1bf, nullptr,
        nullptr, nullptr, nullptr, 2048, 512);
    // ff2 + residual
    float* xout = (l == DEPTHL - 1) ? (float*)d_out : xc;
    if (fits) {
      gemm_k<3, 64><<<dim3(512 / 64, ROWS / 128, 4), 256, 0, stream>>>(
          h1bf, wtF2 + (size_t)l * 512 * 2048, nullptr, nullptr, nullptr, nullptr, part,
          nullptr, nullptr, nullptr, 512, 2048);
      comb_k<4><<<ROWS * 512 / 1024, 256, 0, stream>>>(part, ff_b2 + l * DIMM, xc, xout);
    } else {
      gemm_k<2, 64><<<dim3(512 / 64, ROWS / 128), 256, 0, stream>>>(
          h1bf, wtF2 + (size_t)l * 512 * 2048, ff_b2 + l * DIMM, xc, xout, nullptr, nullptr,
          nullptr, nullptr, nullptr, 512, 2048);
    }
  }
}